// Round 1
// baseline (59.144 us; speedup 1.0000x reference)
//
#include <hip/hip_runtime.h>

#define HH 1024
#define WW 1024
#define BB 8

__global__ __launch_bounds__(256) void getaffs_kernel(const float* __restrict__ seg,
                                                      float* __restrict__ out) {
    const int row_id = blockIdx.x;          // b*HH + i
    const int b = row_id >> 10;
    const int i = row_id & (HH - 1);
    const int j = threadIdx.x << 2;         // columns j..j+3

    const float* srow = seg + (size_t)row_id * WW;
    const float4 c = *reinterpret_cast<const float4*>(srow + j);
    const float cc[4] = {c.x, c.y, c.z, c.w};

    const size_t plane = (size_t)BB * HH * WW;       // elements per offset plane
    float* op = out + (size_t)row_id * WW + j;       // position inside a plane

    const int ds[4] = {1, 3, 9, 27};

    // Row offsets (-d, 0): output planes 0, 2, 4, 6
    #pragma unroll
    for (int k = 0; k < 4; ++k) {
        const int d = ds[k];
        float4 r;
        if (i - d >= 0) {
            r = *reinterpret_cast<const float4*>(seg + ((size_t)b * HH + (i - d)) * WW + j);
        } else {
            r = make_float4(0.f, 0.f, 0.f, 0.f);
        }
        float4 o;
        o.x = (r.x == c.x) ? 1.f : 0.f;
        o.y = (r.y == c.y) ? 1.f : 0.f;
        o.z = (r.z == c.z) ? 1.f : 0.f;
        o.w = (r.w == c.w) ? 1.f : 0.f;
        *reinterpret_cast<float4*>(op + (size_t)(2 * k) * plane) = o;
    }

    // Col offsets (0, -d): output planes 1, 3, 5, 7
    #pragma unroll
    for (int k = 0; k < 4; ++k) {
        const int d = ds[k];
        float o[4];
        #pragma unroll
        for (int t = 0; t < 4; ++t) {
            const int col = j + t - d;
            const float v = (col >= 0) ? srow[col] : 0.f;
            o[t] = (v == cc[t]) ? 1.f : 0.f;
        }
        float4 ov = make_float4(o[0], o[1], o[2], o[3]);
        *reinterpret_cast<float4*>(op + (size_t)(2 * k + 1) * plane) = ov;
    }
}

extern "C" void kernel_launch(void* const* d_in, const int* in_sizes, int n_in,
                              void* d_out, int out_size, void* d_ws, size_t ws_size,
                              hipStream_t stream) {
    const float* seg = (const float*)d_in[0];
    float* out = (float*)d_out;
    dim3 grid(BB * HH);
    dim3 block(WW / 4);
    getaffs_kernel<<<grid, block, 0, stream>>>(seg, out);
}

// Round 3
// 54.165 us; speedup vs baseline: 1.0919x; 1.0919x over previous
//
#include <hip/hip_runtime.h>

#define HH 1024
#define WW 1024
#define BB 8

typedef float v4f __attribute__((ext_vector_type(4)));

__global__ __launch_bounds__(256) void getaffs_kernel(const float* __restrict__ seg,
                                                      float* __restrict__ out) {
    // XCD-chunked swizzle: blocks round-robin across 8 XCDs, so give XCD x the
    // contiguous row chunk [x*1024, (x+1)*1024) — exactly one 4 MB batch image,
    // which fits that XCD's private L2. All shifted-row reads become L2 hits.
    const int bid = blockIdx.x;
    const int row_id = ((bid & 7) << 10) + (bid >> 3);   // b*HH + i
    const int b = row_id >> 10;
    const int i = row_id & (HH - 1);
    const int j = threadIdx.x << 2;         // columns j..j+3

    const float* srow = seg + (size_t)row_id * WW;
    const v4f c = *reinterpret_cast<const v4f*>(srow + j);

    const size_t plane = (size_t)BB * HH * WW;       // elements per offset plane
    float* op = out + (size_t)row_id * WW + j;       // position inside a plane

    const int ds[4] = {1, 3, 9, 27};

    // Row offsets (-d, 0): output planes 0, 2, 4, 6
    #pragma unroll
    for (int k = 0; k < 4; ++k) {
        const int d = ds[k];
        v4f r;
        if (i - d >= 0) {
            r = *reinterpret_cast<const v4f*>(seg + ((size_t)b * HH + (i - d)) * WW + j);
        } else {
            r = (v4f){0.f, 0.f, 0.f, 0.f};
        }
        v4f o;
        o.x = (r.x == c.x) ? 1.f : 0.f;
        o.y = (r.y == c.y) ? 1.f : 0.f;
        o.z = (r.z == c.z) ? 1.f : 0.f;
        o.w = (r.w == c.w) ? 1.f : 0.f;
        __builtin_nontemporal_store(o, reinterpret_cast<v4f*>(op + (size_t)(2 * k) * plane));
    }

    // Col offsets (0, -d): output planes 1, 3, 5, 7
    #pragma unroll
    for (int k = 0; k < 4; ++k) {
        const int d = ds[k];
        v4f o;
        #pragma unroll
        for (int t = 0; t < 4; ++t) {
            const int col = j + t - d;
            const float v = (col >= 0) ? srow[col] : 0.f;
            o[t] = (v == c[t]) ? 1.f : 0.f;
        }
        __builtin_nontemporal_store(o, reinterpret_cast<v4f*>(op + (size_t)(2 * k + 1) * plane));
    }
}

extern "C" void kernel_launch(void* const* d_in, const int* in_sizes, int n_in,
                              void* d_out, int out_size, void* d_ws, size_t ws_size,
                              hipStream_t stream) {
    const float* seg = (const float*)d_in[0];
    float* out = (float*)d_out;
    dim3 grid(BB * HH);
    dim3 block(WW / 4);
    getaffs_kernel<<<grid, block, 0, stream>>>(seg, out);
}

// Round 4
// 52.588 us; speedup vs baseline: 1.1246x; 1.0300x over previous
//
#include <hip/hip_runtime.h>

#define HH 1024
#define WW 1024
#define BB 8

typedef float v4f __attribute__((ext_vector_type(4)));

__global__ __launch_bounds__(256) void getaffs_kernel(const float* __restrict__ seg,
                                                      float* __restrict__ out) {
    // XCD-chunked swizzle: round-robin dispatch means bid%8 = XCD, so give XCD x
    // the contiguous row chunk [x*1024,(x+1)*1024) — one 4 MB batch image, which
    // fits its private L2. All shifted-row reads are then L2 hits.
    const int bid = blockIdx.x;
    const int row_id = ((bid & 7) << 10) + (bid >> 3);   // b*HH + i
    const int b = row_id >> 10;
    const int i = row_id & (HH - 1);
    const int j = threadIdx.x << 2;         // columns j..j+3

    const float* srow = seg + (size_t)row_id * WW;
    const v4f c = *reinterpret_cast<const v4f*>(srow + j);

    const size_t plane = (size_t)BB * HH * WW;       // elements per offset plane
    float* op = out + (size_t)row_id * WW + j;       // position inside a plane

    const int ds[4] = {1, 3, 9, 27};

    // Row offsets (-d, 0): output planes 0, 2, 4, 6 — aligned vector loads.
    #pragma unroll
    for (int k = 0; k < 4; ++k) {
        const int d = ds[k];
        v4f r;
        if (i - d >= 0) {
            r = *reinterpret_cast<const v4f*>(seg + ((size_t)b * HH + (i - d)) * WW + j);
        } else {
            r = (v4f){0.f, 0.f, 0.f, 0.f};
        }
        v4f o;
        o.x = (r.x == c.x) ? 1.f : 0.f;
        o.y = (r.y == c.y) ? 1.f : 0.f;
        o.z = (r.z == c.z) ? 1.f : 0.f;
        o.w = (r.w == c.w) ? 1.f : 0.f;
        __builtin_nontemporal_store(o, reinterpret_cast<v4f*>(op + (size_t)(2 * k) * plane));
    }

    // Col offsets (0, -d): output planes 1, 3, 5, 7 — one (unaligned-16B,
    // 4B-aligned) vector load covers cols j-d..j+3-d. Guarded scalar fallback
    // only for the left edge (j < d), i.e. lanes 0..6 of wave 0.
    #pragma unroll
    for (int k = 0; k < 4; ++k) {
        const int d = ds[k];
        v4f o;
        if (j >= d) {
            const v4f s = *reinterpret_cast<const v4f*>(srow + (j - d));
            o.x = (s.x == c.x) ? 1.f : 0.f;
            o.y = (s.y == c.y) ? 1.f : 0.f;
            o.z = (s.z == c.z) ? 1.f : 0.f;
            o.w = (s.w == c.w) ? 1.f : 0.f;
        } else {
            #pragma unroll
            for (int t = 0; t < 4; ++t) {
                const int col = j + t - d;
                const float v = (col >= 0) ? srow[col] : 0.f;
                o[t] = (v == c[t]) ? 1.f : 0.f;
            }
        }
        __builtin_nontemporal_store(o, reinterpret_cast<v4f*>(op + (size_t)(2 * k + 1) * plane));
    }
}

extern "C" void kernel_launch(void* const* d_in, const int* in_sizes, int n_in,
                              void* d_out, int out_size, void* d_ws, size_t ws_size,
                              hipStream_t stream) {
    const float* seg = (const float*)d_in[0];
    float* out = (float*)d_out;
    dim3 grid(BB * HH);
    dim3 block(WW / 4);
    getaffs_kernel<<<grid, block, 0, stream>>>(seg, out);
}